// Round 8
// baseline (229.948 us; speedup 1.0000x reference)
//
#include <hip/hip_runtime.h>

// Laplacian pyramid loss, 3 levels, B*C = 48 channels of 512x512 f32.
// R16: R15 with 32x64 output tiles (512 threads/block) in loss_kernel.
//  - per-output instruction cut: staging redundancy 1.55 -> 1.34, phase-E
//    overscan 1.375 -> 1.19, per-block fixed cost (decode/barriers/reduce)
//    halved per output. Blocks 18960 -> 10224.
//  - LDS 29.0 KB -> 4 blocks/CU x 512 = 2048 thr/CU (full, same as R15).
//  - all FP expressions unchanged (bit-identical partials); finalize sum
//    stays index-ordered. Down kernels verbatim R14.

#define NCH 48

__device__ __forceinline__ int refl(int p, int n) {
  return p < 0 ? -p : (p >= n ? 2 * n - 2 - p : p);
}
// down-space reflect: dref(j,n) == refl(2j, 2n) >> 1  (half-sample at right)
__device__ __forceinline__ int dref(int j, int n) {
  return j < 0 ? -j : (j >= n ? 2 * n - 1 - j : j);
}

// ---------------- down kernel: dst = downsample2(gauss5x5_reflect(src)) ----
// 1D grid, XCD-chunked swizzle. tl = log2(tiles_per_side).
__global__ __launch_bounds__(256) void down_kernel(
    const float* __restrict__ src_a, const float* __restrict__ src_b,
    float* __restrict__ dst_a, float* __restrict__ dst_b, int H, int tl)
{
  const int W = H, W2 = W >> 1;
  const int tps = 1 << tl, nt = tps * tps;
  const int total = 96 * nt;
  const int bid = blockIdx.x;
  const int s = (bid & 7) * (total >> 3) + (bid >> 3);   // XCD chunk
  const int z = s >> (2 * tl);
  const int rm = s & (nt - 1);
  const int by = rm >> tl, bx = rm & (tps - 1);

  const int ch = (z >= NCH) ? z - NCH : z;
  const float* src = ((z >= NCH) ? src_b : src_a) + (size_t)ch * H * W;
  float* dst = ((z >= NCH) ? dst_b : dst_a) + (size_t)ch * W2 * W2;
  const int tid = threadIdx.x;

  __shared__ __align__(16) float s_h[67][34];

  const int rb = 64 * by - 2;
  const int C0 = 64 * bx - 4;
  const bool lft = (bx == 0);
  const bool rgt = (64 * bx + 64 >= W);

  for (int t = tid; t < 67 * 18; t += 256) {
    int r = t / 18, c4 = t - 18 * r;
    int gr = refl(rb + r, H);
    int gb = min(max(C0 + 4 * c4, 0), W - 4);
    float4 v = *reinterpret_cast<const float4*>(src + (size_t)gr * W + gb);
    float pz = __shfl_up(v.z, 1);
    float pw = __shfl_up(v.w, 1);
    float nx = __shfl_down(v.x, 1);
    if (c4 >= 1 && c4 <= 16) {
      float hb0;
      if (lft && c4 == 1)
        hb0 = v.z + 4.f * v.y + 6.f * v.x + 4.f * v.y + v.z;   // m=0 reflect
      else
        hb0 = pz + 4.f * pw + 6.f * v.x + 4.f * v.y + v.z;
      float nxe = (rgt && c4 == 16) ? v.z : nx;                // m=W-2 reflect
      float hb1 = v.x + 4.f * v.y + 6.f * v.z + 4.f * v.w + nxe;
      *reinterpret_cast<float2*>(&s_h[r][2 * c4 - 2]) = make_float2(hb0, hb1);
    }
  }
  __syncthreads();

  {
    int r = tid >> 3, g = tid & 7;
    float4 h0 = *reinterpret_cast<const float4*>(&s_h[2 * r][4 * g]);
    float4 h1 = *reinterpret_cast<const float4*>(&s_h[2 * r + 1][4 * g]);
    float4 h2 = *reinterpret_cast<const float4*>(&s_h[2 * r + 2][4 * g]);
    float4 h3 = *reinterpret_cast<const float4*>(&s_h[2 * r + 3][4 * g]);
    float4 h4 = *reinterpret_cast<const float4*>(&s_h[2 * r + 4][4 * g]);
    float4 o;
    o.x = (h0.x + h4.x + 6.f * h2.x + 4.f * (h1.x + h3.x)) * (1.f / 256.f);
    o.y = (h0.y + h4.y + 6.f * h2.y + 4.f * (h1.y + h3.y)) * (1.f / 256.f);
    o.z = (h0.z + h4.z + 6.f * h2.z + 4.f * (h1.z + h3.z)) * (1.f / 256.f);
    o.w = (h0.w + h4.w + 6.f * h2.w + 4.f * (h1.w + h3.w)) * (1.f / 256.f);
    *reinterpret_cast<float4*>(dst + (size_t)(32 * by + r) * W2 + 32 * bx + 4 * g) = o;
  }
}

// ---------------- merged loss kernel: all 3 levels, 32x64 tiles ------------
// per-channel tiles: L0 17y*9x=153, L1 9y*5x=45, L2 5y*3x=15 -> 213
// NPART = 48*213 = 10224 = 8*1278
__global__ __launch_bounds__(512) void loss_kernel(
    const float* __restrict__ in, const float* __restrict__ tg,
    const float* __restrict__ d0i, const float* __restrict__ d0t,
    const float* __restrict__ d1i, const float* __restrict__ d1t,
    const float* __restrict__ d2i, const float* __restrict__ d2t,
    double* __restrict__ partials)
{
  const int bid = blockIdx.x;
  const int swz = (bid & 7) * 1278 + (bid >> 3);
  const int z = swz / 213;
  int tb = swz - 213 * z;
  int lvl, bx, by;
  if (tb < 153) { lvl = 0; by = tb / 9; bx = tb - 9 * by; }
  else if (tb < 198) { int u = tb - 153; lvl = 1; by = u / 5; bx = u - 5 * by; }
  else { int u = tb - 198; lvl = 2; by = u / 3; bx = u - 3 * by; }

  const int H = 512 >> lvl, W = H, HO = H + 2, H2 = H >> 1, W2 = W >> 1;
  const float* cb0 = (lvl == 0) ? in : (lvl == 1) ? d0i : d1i;
  const float* cb1 = (lvl == 0) ? tg : (lvl == 1) ? d0t : d1t;
  const float* db0 = (lvl == 0) ? d0i : (lvl == 1) ? d1i : d2i;
  const float* db1 = (lvl == 0) ? d0t : (lvl == 1) ? d1t : d2t;
  const float* curp[2] = {cb0 + (size_t)z * H * W, cb1 + (size_t)z * H * W};
  const float* dwp[2] = {db0 + (size_t)z * H2 * W2, db1 + (size_t)z * H2 * W2};
  const float scale = 1.f / (float)(NCH * HO * HO);

  const int x0 = bx * 64, y0 = by * 32;
  const int tid = threadIdx.x;

  __shared__ __align__(16) float s_diff[2][36][76];   // 21.9 KB
  __shared__ __align__(16) float s_down[2][20][44];   //  7.0 KB

  // fixed fast-path geometry for ALL tiles.
  // s_diff col c <-> cur col (x0-4)+c  (19 staged float4 groups, cols 0..75)
  const int cbase = x0 - 4, rbase = y0 - 2;
  const int dr0 = (y0 >> 1) - 2, du0 = (x0 >> 1) - 4;
  // staged spans: cur x0-4..x0+71, down du0..du0+43 -> interior iff x0+96<=W
  const bool vec = (x0 >= 64) && (x0 + 96 <= W);
  const int x_end = min(HO, x0 + 64), y_end = min(HO, y0 + 32);

  // ---- phase A: stage s_diff (cur window) + s_down, reflect folded in ----
  if (vec) {
    for (int t = tid; t < 1368; t += 512) {       // 2 img * 36 rows * 19 groups
      int img = t >= 684; int j = t - (img ? 684 : 0);
      int l = j / 19, g = j - 19 * l;
      int gr = refl(rbase + l, H);
      *reinterpret_cast<float4*>(&s_diff[img][l][4 * g]) =
          *reinterpret_cast<const float4*>(curp[img] + (size_t)gr * W + cbase + 4 * g);
    }
    if (tid < 440) {                              // 2 img * 20 rows * 11 groups
      int img = tid >= 220; int j = tid - (img ? 220 : 0);
      int k = j / 11, g = j - 11 * k;
      int gr = dref(dr0 + k, H2);
      *reinterpret_cast<float4*>(&s_down[img][k][4 * g]) =
          *reinterpret_cast<const float4*>(dwp[img] + (size_t)gr * W2 + du0 + 4 * g);
    }
  } else {
    // group-vectorized edge staging: each float4 group is purely forward
    // (aligned load) or reflected (scalar fallback)
    for (int t = tid; t < 1368; t += 512) {
      int img = t >= 684; int j = t - (img ? 684 : 0);
      int l = j / 19, g = j - 19 * l;
      int gr = refl(rbase + l, H);
      const float* rowp = curp[img] + (size_t)gr * W;
      int p0 = cbase + 4 * g;
      float4 v;
      if (p0 >= 0 && p0 + 3 < W) {
        v = *reinterpret_cast<const float4*>(rowp + p0);
      } else {
        v.x = rowp[refl(p0, W)];
        v.y = rowp[refl(p0 + 1, W)];
        v.z = rowp[refl(p0 + 2, W)];
        v.w = rowp[refl(p0 + 3, W)];
      }
      *reinterpret_cast<float4*>(&s_diff[img][l][4 * g]) = v;
    }
    if (tid < 440) {
      int img = tid >= 220; int j = tid - (img ? 220 : 0);
      int k = j / 11, g = j - 11 * k;
      int gr = dref(dr0 + k, H2);
      const float* rowp = dwp[img] + (size_t)gr * W2;
      int p0 = du0 + 4 * g;
      float4 v;
      if (p0 >= 0 && p0 + 3 < W2) {
        v = *reinterpret_cast<const float4*>(rowp + p0);
      } else {
        v.x = rowp[dref(p0, W2)];
        v.y = rowp[dref(p0 + 1, W2)];
        v.z = rowp[dref(p0 + 2, W2)];
        v.w = rowp[dref(p0 + 3, W2)];
      }
      *reinterpret_cast<float4*>(&s_down[img][k][4 * g]) = v;
    }
  }
  __syncthreads();

  // ---- phase E (fused D): vertical+horizontal up + diff over s_diff ----
  for (int t = tid; t < 1368; t += 512) {
    int img = t / 684, j = t - 684 * img;
    int l = j / 19, c4 = j - 19 * l;
    float4 c = *reinterpret_cast<const float4*>(&s_diff[img][l][4 * c4]);
    const int par = l & 1;
    const int rr = (l + par) >> 1;
    const int d0 = 2 * c4 + 1;                    // du of Tm1 (max 2*18+4=40<44)
    const float* rA = s_down[img][rr];
    const float* rB = s_down[img][rr + 1];
    float Tm1, T0, T1, T2;
    if (par) {
      Tm1 = 0.5f * (rA[d0] + rB[d0]);
      T0  = 0.5f * (rA[d0 + 1] + rB[d0 + 1]);
      T1  = 0.5f * (rA[d0 + 2] + rB[d0 + 2]);
      T2  = 0.5f * (rA[d0 + 3] + rB[d0 + 3]);
    } else {
      const float* rC = s_down[img][rr + 2];
      Tm1 = 0.125f * (rA[d0] + rC[d0]) + 0.75f * rB[d0];
      T0  = 0.125f * (rA[d0 + 1] + rC[d0 + 1]) + 0.75f * rB[d0 + 1];
      T1  = 0.125f * (rA[d0 + 2] + rC[d0 + 2]) + 0.75f * rB[d0 + 2];
      T2  = 0.125f * (rA[d0 + 3] + rC[d0 + 3]) + 0.75f * rB[d0 + 3];
    }
    float4 d;
    d.x = c.x - (0.125f * (Tm1 + T1) + 0.75f * T0);
    d.y = c.y - 0.5f * (T0 + T1);
    d.z = c.z - (0.125f * (T0 + T2) + 0.75f * T1);
    d.w = c.w - 0.5f * (T1 + T2);
    *reinterpret_cast<float4*>(&s_diff[img][l][4 * c4]) = d;
  }
  __syncthreads();

  // ---- phase F: 3x3 |gx|+|gy| miniloss, |in - tg| (separable, masked) ----
  float val = 0.f;
  {
    const int tx = tid & 15, ty = tid >> 4;       // 16 x-groups, 32 rows
    const int yy = y0 + ty;
    if (yy < y_end) {
      float ab[2][4];
#pragma unroll
      for (int img = 0; img < 2; ++img) {
        float a[3][6];
#pragma unroll
        for (int r = 0; r < 3; ++r) {
          const float* row = s_diff[img][ty + r];
          float2 L = *reinterpret_cast<const float2*>(&row[4 * tx + 2]);
          float4 R = *reinterpret_cast<const float4*>(&row[4 * tx + 4]);
          a[r][0] = L.x; a[r][1] = L.y; a[r][2] = R.x;
          a[r][3] = R.y; a[r][4] = R.z; a[r][5] = R.w;
        }
        float s[6], d[6], v[6];
#pragma unroll
        for (int k = 0; k < 6; ++k) {
          s[k] = a[0][k] + a[2][k];
          d[k] = a[0][k] - a[2][k];
          v[k] = 2.f * s[k] + 4.f * a[1][k];
        }
#pragma unroll
        for (int jj = 0; jj < 4; ++jj) {
          float gx = v[jj] - v[jj + 2];
          float u  = (d[jj] + d[jj + 2]) + 2.f * d[jj + 1];
          ab[img][jj] = fabsf(gx) + 2.f * fabsf(u);
        }
      }
      const int xb = x0 + 4 * tx;
#pragma unroll
      for (int jj = 0; jj < 4; ++jj)
        if (xb + jj < x_end) val += fabsf(ab[0][jj] - ab[1][jj]);
    }
  }
  val *= scale;

  // ---- reduction -> per-block partial slot ----
#pragma unroll
  for (int off = 32; off > 0; off >>= 1) val += __shfl_down(val, off, 64);
  __shared__ float wpart[8];
  if ((tid & 63) == 0) wpart[tid >> 6] = val;
  __syncthreads();
  if (tid == 0) {
    double s = 0.0;
#pragma unroll
    for (int i = 0; i < 8; ++i) s += (double)wpart[i];
    partials[swz] = s;
  }
}

__global__ __launch_bounds__(1024) void finalize_kernel(
    const double* __restrict__ partials, int N, float* __restrict__ out)
{
  double s = 0.0;
  for (int i = threadIdx.x; i < N; i += 1024) s += partials[i];
#pragma unroll
  for (int off = 32; off > 0; off >>= 1)
    s += __shfl_down(s, off, 64);
  __shared__ double wp[16];
  if ((threadIdx.x & 63) == 0) wp[threadIdx.x >> 6] = s;
  __syncthreads();
  if (threadIdx.x == 0) {
    double t = 0.0;
#pragma unroll
    for (int i = 0; i < 16; ++i) t += wp[i];
    out[0] = (float)t;
  }
}

extern "C" void kernel_launch(void* const* d_in, const int* in_sizes, int n_in,
                              void* d_out, int out_size, void* d_ws, size_t ws_size,
                              hipStream_t stream) {
  const float* in = (const float*)d_in[0];
  const float* tg = (const float*)d_in[1];
  float* out = (float*)d_out;

  const int NPART = 10224;   // 48 * (153 + 45 + 15)
  double* partials = (double*)d_ws;
  float* base = (float*)((char*)d_ws + (size_t)NPART * sizeof(double));
  const size_t s0 = (size_t)NCH * 256 * 256;
  const size_t s1 = (size_t)NCH * 128 * 128;
  float* d0i = base;
  float* d0t = d0i + s0;
  float* d1i = d0t + s0;
  float* d1t = d1i + s1;
  float* d2i = d1t + s1;
  float* d2t = d2i + (size_t)NCH * 64 * 64;

  down_kernel<<<dim3(6144), dim3(256), 0, stream>>>(in, tg, d0i, d0t, 512, 3);
  down_kernel<<<dim3(1536), dim3(256), 0, stream>>>(d0i, d0t, d1i, d1t, 256, 2);
  down_kernel<<<dim3(384), dim3(256), 0, stream>>>(d1i, d1t, d2i, d2t, 128, 1);

  loss_kernel<<<dim3(10224), dim3(512), 0, stream>>>(
      in, tg, d0i, d0t, d1i, d1t, d2i, d2t, partials);

  finalize_kernel<<<1, dim3(1024), 0, stream>>>(partials, NPART, out);
}

// Round 9
// 227.541 us; speedup vs baseline: 1.0106x; 1.0106x over previous
//
#include <hip/hip_runtime.h>

// Laplacian pyramid loss, 3 levels, B*C = 48 channels of 512x512 f32.
// R17: revert R16's 32x64 tiles (regressed) -> R15 32x32/256thr shape.
// Phase E rewritten as pair-of-groups (8 cols/item, 360 items):
//  - tap reads were ALL odd-word-offset (d0=2c4+1, stride%4==0) -> every
//    lane on odd banks = structural >=4-way conflict. Now float2 loads at
//    even offsets 4p+2e (8B-aligned, even+odd banks).
//  - two-group tap overlap dedupes 2/8 vertical combos.
//  - identical FP expressions -> bit-identical partials.

#define NCH 48

__device__ __forceinline__ int refl(int p, int n) {
  return p < 0 ? -p : (p >= n ? 2 * n - 2 - p : p);
}
// down-space reflect: dref(j,n) == refl(2j, 2n) >> 1  (half-sample at right)
__device__ __forceinline__ int dref(int j, int n) {
  return j < 0 ? -j : (j >= n ? 2 * n - 1 - j : j);
}

// ---------------- down kernel: dst = downsample2(gauss5x5_reflect(src)) ----
// 1D grid, XCD-chunked swizzle. tl = log2(tiles_per_side).
__global__ __launch_bounds__(256) void down_kernel(
    const float* __restrict__ src_a, const float* __restrict__ src_b,
    float* __restrict__ dst_a, float* __restrict__ dst_b, int H, int tl)
{
  const int W = H, W2 = W >> 1;
  const int tps = 1 << tl, nt = tps * tps;
  const int total = 96 * nt;
  const int bid = blockIdx.x;
  const int s = (bid & 7) * (total >> 3) + (bid >> 3);   // XCD chunk
  const int z = s >> (2 * tl);
  const int rm = s & (nt - 1);
  const int by = rm >> tl, bx = rm & (tps - 1);

  const int ch = (z >= NCH) ? z - NCH : z;
  const float* src = ((z >= NCH) ? src_b : src_a) + (size_t)ch * H * W;
  float* dst = ((z >= NCH) ? dst_b : dst_a) + (size_t)ch * W2 * W2;
  const int tid = threadIdx.x;

  __shared__ __align__(16) float s_h[67][34];

  const int rb = 64 * by - 2;
  const int C0 = 64 * bx - 4;
  const bool lft = (bx == 0);
  const bool rgt = (64 * bx + 64 >= W);

  for (int t = tid; t < 67 * 18; t += 256) {
    int r = t / 18, c4 = t - 18 * r;
    int gr = refl(rb + r, H);
    int gb = min(max(C0 + 4 * c4, 0), W - 4);
    float4 v = *reinterpret_cast<const float4*>(src + (size_t)gr * W + gb);
    float pz = __shfl_up(v.z, 1);
    float pw = __shfl_up(v.w, 1);
    float nx = __shfl_down(v.x, 1);
    if (c4 >= 1 && c4 <= 16) {
      float hb0;
      if (lft && c4 == 1)
        hb0 = v.z + 4.f * v.y + 6.f * v.x + 4.f * v.y + v.z;   // m=0 reflect
      else
        hb0 = pz + 4.f * pw + 6.f * v.x + 4.f * v.y + v.z;
      float nxe = (rgt && c4 == 16) ? v.z : nx;                // m=W-2 reflect
      float hb1 = v.x + 4.f * v.y + 6.f * v.z + 4.f * v.w + nxe;
      *reinterpret_cast<float2*>(&s_h[r][2 * c4 - 2]) = make_float2(hb0, hb1);
    }
  }
  __syncthreads();

  {
    int r = tid >> 3, g = tid & 7;
    float4 h0 = *reinterpret_cast<const float4*>(&s_h[2 * r][4 * g]);
    float4 h1 = *reinterpret_cast<const float4*>(&s_h[2 * r + 1][4 * g]);
    float4 h2 = *reinterpret_cast<const float4*>(&s_h[2 * r + 2][4 * g]);
    float4 h3 = *reinterpret_cast<const float4*>(&s_h[2 * r + 3][4 * g]);
    float4 h4 = *reinterpret_cast<const float4*>(&s_h[2 * r + 4][4 * g]);
    float4 o;
    o.x = (h0.x + h4.x + 6.f * h2.x + 4.f * (h1.x + h3.x)) * (1.f / 256.f);
    o.y = (h0.y + h4.y + 6.f * h2.y + 4.f * (h1.y + h3.y)) * (1.f / 256.f);
    o.z = (h0.z + h4.z + 6.f * h2.z + 4.f * (h1.z + h3.z)) * (1.f / 256.f);
    o.w = (h0.w + h4.w + 6.f * h2.w + 4.f * (h1.w + h3.w)) * (1.f / 256.f);
    *reinterpret_cast<float4*>(dst + (size_t)(32 * by + r) * W2 + 32 * bx + 4 * g) = o;
  }
}

// ---------------- merged loss kernel: all 3 levels, unified fast tile ------
__global__ __launch_bounds__(256) void loss_kernel(
    const float* __restrict__ in, const float* __restrict__ tg,
    const float* __restrict__ d0i, const float* __restrict__ d0t,
    const float* __restrict__ d1i, const float* __restrict__ d1t,
    const float* __restrict__ d2i, const float* __restrict__ d2t,
    double* __restrict__ partials)
{
  // XCD-chunked bijective swizzle: 18960 = 8 * 2370
  const int bid = blockIdx.x;
  const int swz = (bid & 7) * 2370 + (bid >> 3);
  const int z = swz / 395;
  int tb = swz - 395 * z;
  int lvl, bx, by;
  if (tb < 289) { lvl = 0; by = tb / 17; bx = tb - 17 * by; }
  else if (tb < 370) { int u = tb - 289; lvl = 1; by = u / 9; bx = u - 9 * by; }
  else { int u = tb - 370; lvl = 2; by = u / 5; bx = u - 5 * by; }

  const int H = 512 >> lvl, W = H, HO = H + 2, H2 = H >> 1, W2 = W >> 1;
  const float* cb0 = (lvl == 0) ? in : (lvl == 1) ? d0i : d1i;
  const float* cb1 = (lvl == 0) ? tg : (lvl == 1) ? d0t : d1t;
  const float* db0 = (lvl == 0) ? d0i : (lvl == 1) ? d1i : d2i;
  const float* db1 = (lvl == 0) ? d0t : (lvl == 1) ? d1t : d2t;
  const float* curp[2] = {cb0 + (size_t)z * H * W, cb1 + (size_t)z * H * W};
  const float* dwp[2] = {db0 + (size_t)z * H2 * W2, db1 + (size_t)z * H2 * W2};
  const float scale = 1.f / (float)(NCH * HO * HO);

  const int x0 = bx * 32, y0 = by * 32;
  const int tid = threadIdx.x;

  __shared__ __align__(16) float s_diff[2][36][44];   // 12.4 KB
  __shared__ __align__(16) float s_down[2][20][24];   //  3.8 KB

  // fixed fast-path geometry for ALL tiles.
  // s_diff col c <-> cur col (x0-4)+c  (10 staged float4 groups, cols 0..39)
  const int cbase = x0 - 4, rbase = y0 - 2;
  const int dr0 = (y0 >> 1) - 2, du0 = (x0 >> 1) - 4;
  const bool vec = (x0 >= 32) && (x0 + 40 <= W);
  const int x_end = min(HO, x0 + 32), y_end = min(HO, y0 + 32);

  // ---- phase A: stage s_diff (cur window) + s_down, reflect folded in ----
  if (vec) {
    for (int t = tid; t < 720; t += 256) {        // 2 img * 36 rows * 10 groups
      int img = t >= 360; int j = t - (img ? 360 : 0);
      int l = j / 10, g = j - 10 * l;
      int gr = refl(rbase + l, H);
      *reinterpret_cast<float4*>(&s_diff[img][l][4 * g]) =
          *reinterpret_cast<const float4*>(curp[img] + (size_t)gr * W + cbase + 4 * g);
    }
    if (tid < 240) {                              // 2 img * 20 rows * 6 groups
      int img = tid >= 120; int j = tid - (img ? 120 : 0);
      int k = j / 6, g = j - 6 * k;
      int gr = dref(dr0 + k, H2);
      *reinterpret_cast<float4*>(&s_down[img][k][4 * g]) =
          *reinterpret_cast<const float4*>(dwp[img] + (size_t)gr * W2 + du0 + 4 * g);
    }
  } else {
    // group-vectorized edge staging: each float4 group is purely forward
    // (aligned load) or reflected (scalar fallback)
    for (int t = tid; t < 720; t += 256) {
      int img = t >= 360; int j = t - (img ? 360 : 0);
      int l = j / 10, g = j - 10 * l;
      int gr = refl(rbase + l, H);
      const float* rowp = curp[img] + (size_t)gr * W;
      int p0 = cbase + 4 * g;
      float4 v;
      if (p0 >= 0 && p0 + 3 < W) {
        v = *reinterpret_cast<const float4*>(rowp + p0);
      } else {
        v.x = rowp[refl(p0, W)];
        v.y = rowp[refl(p0 + 1, W)];
        v.z = rowp[refl(p0 + 2, W)];
        v.w = rowp[refl(p0 + 3, W)];
      }
      *reinterpret_cast<float4*>(&s_diff[img][l][4 * g]) = v;
    }
    if (tid < 240) {
      int img = tid >= 120; int j = tid - (img ? 120 : 0);
      int k = j / 6, g = j - 6 * k;
      int gr = dref(dr0 + k, H2);
      const float* rowp = dwp[img] + (size_t)gr * W2;
      int p0 = du0 + 4 * g;
      float4 v;
      if (p0 >= 0 && p0 + 3 < W2) {
        v = *reinterpret_cast<const float4*>(rowp + p0);
      } else {
        v.x = rowp[dref(p0, W2)];
        v.y = rowp[dref(p0 + 1, W2)];
        v.z = rowp[dref(p0 + 2, W2)];
        v.w = rowp[dref(p0 + 3, W2)];
      }
      *reinterpret_cast<float4*>(&s_down[img][k][4 * g]) = v;
    }
  }
  __syncthreads();

  // ---- phase E (fused D): pair-of-groups, even-aligned float2 tap reads ---
  // item = (img, row l, pair p): cols 8p..8p+7. Unique taps T(d), d=4p+1..
  // 4p+6, read via float2 at even offsets 4p+2e (s_down stride 24 % 4 == 0).
  for (int t = tid; t < 360; t += 256) {
    int img = t / 180, j = t - 180 * img;
    int l = j / 5, p = j - 5 * l;
    const int par = l & 1;
    const int rr = (l + par) >> 1;
    const int b0 = 4 * p;
    const float* rA = s_down[img][rr];
    const float* rB = s_down[img][rr + 1];
    float2 a0 = *reinterpret_cast<const float2*>(&rA[b0]);
    float2 a1 = *reinterpret_cast<const float2*>(&rA[b0 + 2]);
    float2 a2 = *reinterpret_cast<const float2*>(&rA[b0 + 4]);
    float2 a3 = *reinterpret_cast<const float2*>(&rA[b0 + 6]);
    float2 q0 = *reinterpret_cast<const float2*>(&rB[b0]);
    float2 q1 = *reinterpret_cast<const float2*>(&rB[b0 + 2]);
    float2 q2 = *reinterpret_cast<const float2*>(&rB[b0 + 4]);
    float2 q3 = *reinterpret_cast<const float2*>(&rB[b0 + 6]);
    // taps T1..T6 correspond to s_down cols 4p+1 .. 4p+6
    float T1, T2, T3, T4, T5, T6;
    if (par) {
      T1 = 0.5f * (a0.y + q0.y);
      T2 = 0.5f * (a1.x + q1.x);
      T3 = 0.5f * (a1.y + q1.y);
      T4 = 0.5f * (a2.x + q2.x);
      T5 = 0.5f * (a2.y + q2.y);
      T6 = 0.5f * (a3.x + q3.x);
    } else {
      const float* rC = s_down[img][rr + 2];
      float2 c0 = *reinterpret_cast<const float2*>(&rC[b0]);
      float2 c1 = *reinterpret_cast<const float2*>(&rC[b0 + 2]);
      float2 c2 = *reinterpret_cast<const float2*>(&rC[b0 + 4]);
      float2 c3 = *reinterpret_cast<const float2*>(&rC[b0 + 6]);
      T1 = 0.125f * (a0.y + c0.y) + 0.75f * q0.y;
      T2 = 0.125f * (a1.x + c1.x) + 0.75f * q1.x;
      T3 = 0.125f * (a1.y + c1.y) + 0.75f * q1.y;
      T4 = 0.125f * (a2.x + c2.x) + 0.75f * q2.x;
      T5 = 0.125f * (a2.y + c2.y) + 0.75f * q2.y;
      T6 = 0.125f * (a3.x + c3.x) + 0.75f * q3.x;
    }
    float* drow = s_diff[img][l];
    // group 0: cols 8p..8p+3, taps (Tm1,T0,T1,T2) = (T1,T2,T3,T4)
    {
      float4 c = *reinterpret_cast<const float4*>(&drow[8 * p]);
      float4 d;
      d.x = c.x - (0.125f * (T1 + T3) + 0.75f * T2);
      d.y = c.y - 0.5f * (T2 + T3);
      d.z = c.z - (0.125f * (T2 + T4) + 0.75f * T3);
      d.w = c.w - 0.5f * (T3 + T4);
      *reinterpret_cast<float4*>(&drow[8 * p]) = d;
    }
    // group 1: cols 8p+4..8p+7, taps (Tm1,T0,T1,T2) = (T3,T4,T5,T6)
    {
      float4 c = *reinterpret_cast<const float4*>(&drow[8 * p + 4]);
      float4 d;
      d.x = c.x - (0.125f * (T3 + T5) + 0.75f * T4);
      d.y = c.y - 0.5f * (T4 + T5);
      d.z = c.z - (0.125f * (T4 + T6) + 0.75f * T5);
      d.w = c.w - 0.5f * (T5 + T6);
      *reinterpret_cast<float4*>(&drow[8 * p + 4]) = d;
    }
  }
  __syncthreads();

  // ---- phase F: 3x3 |gx|+|gy| miniloss, |in - tg| (separable, masked) ----
  float val = 0.f;
  {
    const int tx = tid & 7, ty = tid >> 3;
    const int yy = y0 + ty;
    if (yy < y_end) {
      float ab[2][4];
#pragma unroll
      for (int img = 0; img < 2; ++img) {
        float a[3][6];
#pragma unroll
        for (int r = 0; r < 3; ++r) {
          const float* row = s_diff[img][ty + r];
          float2 L = *reinterpret_cast<const float2*>(&row[4 * tx + 2]);
          float4 R = *reinterpret_cast<const float4*>(&row[4 * tx + 4]);
          a[r][0] = L.x; a[r][1] = L.y; a[r][2] = R.x;
          a[r][3] = R.y; a[r][4] = R.z; a[r][5] = R.w;
        }
        float s[6], d[6], v[6];
#pragma unroll
        for (int k = 0; k < 6; ++k) {
          s[k] = a[0][k] + a[2][k];
          d[k] = a[0][k] - a[2][k];
          v[k] = 2.f * s[k] + 4.f * a[1][k];
        }
#pragma unroll
        for (int jj = 0; jj < 4; ++jj) {
          float gx = v[jj] - v[jj + 2];
          float u  = (d[jj] + d[jj + 2]) + 2.f * d[jj + 1];
          ab[img][jj] = fabsf(gx) + 2.f * fabsf(u);
        }
      }
      const int xb = x0 + 4 * tx;
#pragma unroll
      for (int jj = 0; jj < 4; ++jj)
        if (xb + jj < x_end) val += fabsf(ab[0][jj] - ab[1][jj]);
    }
  }
  val *= scale;

  // ---- reduction -> per-block partial slot ----
#pragma unroll
  for (int off = 32; off > 0; off >>= 1) val += __shfl_down(val, off, 64);
  __shared__ float wpart[4];
  if ((tid & 63) == 0) wpart[tid >> 6] = val;
  __syncthreads();
  if (tid == 0) {
    double s = (double)wpart[0] + (double)wpart[1] + (double)wpart[2] + (double)wpart[3];
    partials[swz] = s;
  }
}

__global__ __launch_bounds__(1024) void finalize_kernel(
    const double* __restrict__ partials, int N, float* __restrict__ out)
{
  double s = 0.0;
  for (int i = threadIdx.x; i < N; i += 1024) s += partials[i];
#pragma unroll
  for (int off = 32; off > 0; off >>= 1)
    s += __shfl_down(s, off, 64);
  __shared__ double wp[16];
  if ((threadIdx.x & 63) == 0) wp[threadIdx.x >> 6] = s;
  __syncthreads();
  if (threadIdx.x == 0) {
    double t = 0.0;
#pragma unroll
    for (int i = 0; i < 16; ++i) t += wp[i];
    out[0] = (float)t;
  }
}

extern "C" void kernel_launch(void* const* d_in, const int* in_sizes, int n_in,
                              void* d_out, int out_size, void* d_ws, size_t ws_size,
                              hipStream_t stream) {
  const float* in = (const float*)d_in[0];
  const float* tg = (const float*)d_in[1];
  float* out = (float*)d_out;

  const int NPART = 18960;   // 48 * (289 + 81 + 25)
  double* partials = (double*)d_ws;
  float* base = (float*)((char*)d_ws + (size_t)NPART * sizeof(double));
  const size_t s0 = (size_t)NCH * 256 * 256;
  const size_t s1 = (size_t)NCH * 128 * 128;
  float* d0i = base;
  float* d0t = d0i + s0;
  float* d1i = d0t + s0;
  float* d1t = d1i + s1;
  float* d2i = d1t + s1;
  float* d2t = d2i + (size_t)NCH * 64 * 64;

  down_kernel<<<dim3(6144), dim3(256), 0, stream>>>(in, tg, d0i, d0t, 512, 3);
  down_kernel<<<dim3(1536), dim3(256), 0, stream>>>(d0i, d0t, d1i, d1t, 256, 2);
  down_kernel<<<dim3(384), dim3(256), 0, stream>>>(d1i, d1t, d2i, d2t, 128, 1);

  loss_kernel<<<dim3(18960), dim3(256), 0, stream>>>(
      in, tg, d0i, d0t, d1i, d1t, d2i, d2t, partials);

  finalize_kernel<<<1, dim3(1024), 0, stream>>>(partials, NPART, out);
}